// Round 9
// baseline (360.648 us; speedup 1.0000x reference)
//
#include <hip/hip_runtime.h>
#include <hip/hip_bf16.h>

// HeadUpdator: fused bilinear-upsample+sigmoid+einsum (MFMA) + per-row gating MLP.
// feat (8,64,256,256) f32, head (8,80,64,1) f32, pred (8,80,128,128) f32
// -> out (8,80,64,1,1) f32.
// Round-9: WAVE SPECIALIZATION. 512-thr blocks: waves 0-3 produce P (pred->
// sigmoid->LDS, dbuf), waves 4-7 consume (feat->regs->MFMA). vmcnt queues are
// per-wave, so the two load streams can no longer drain each other; each
// role's loads are loop-carried arrays (the only pattern the allocator
// reliably keeps in flight, per round-3 evidence).

using bf16x8 = __attribute__((ext_vector_type(8))) short;
using f32x4  = __attribute__((ext_vector_type(4))) float;

#define ROWS  8    // rows per block
#define NPART 32   // blocks per batch (256 blocks total = 1/CU)

#define SCHED_FENCE() __builtin_amdgcn_sched_barrier(0)
#define LGKM_BARRIER() do { \
  asm volatile("s_waitcnt lgkmcnt(0)" ::: "memory"); \
  __builtin_amdgcn_s_barrier(); } while (0)

__device__ __forceinline__ unsigned pk2(float lo, float hi) {
  union { __hip_bfloat162 h2; unsigned u; } cv;
  cv.h2 = __float22bfloat162_rn(make_float2(lo, hi));
  return cv.u;
}
// sigmoid(0.25a + 0.75b), -log2e folded into the lerp weights
__device__ __forceinline__ float sigAB(float a, float b) {
  return __builtin_amdgcn_rcpf(1.0f + __builtin_amdgcn_exp2f(-0.36067376f * a - 1.08202128f * b));
}
// sigmoid(0.75a + 0.25b)
__device__ __forceinline__ float sigBA(float a, float b) {
  return __builtin_amdgcn_rcpf(1.0f + __builtin_amdgcn_exp2f(-1.08202128f * a - 0.36067376f * b));
}

// Producer: consume p0/p1 (pred rows of row x, preloaded), write sigmoid P
// into Pb in MFMA-fragment order; optionally reload p0/p1 for row x+1
// (in-place -> loop-carried live range the allocator keeps in flight).
// Pfrag slot bijection (round-8, measured 0 conflicts):
//   slot = kgw*16 + ((n16 ^ ks ^ (kgw<<1)) & 15).
template<int PAR>
__device__ __forceinline__ void prod_row(
    const float* __restrict__ pbat, unsigned short* __restrict__ Pb,
    float4 (&p0)[10], float4 (&p1)[10],
    int nr0, int nr1, bool reload, int gg, int nb) {
  constexpr float wy0 = PAR ? 0.75f : 0.25f;
  constexpr float wy1 = PAR ? 0.25f : 0.75f;
  #pragma unroll
  for (int i = 0; i < 10; ++i) {
    const int n = nb + 8 * i;
    const float y0 = wy0 * p0[i].x + wy1 * p1[i].x;
    const float y1 = wy0 * p0[i].y + wy1 * p1[i].y;
    const float y2 = wy0 * p0[i].z + wy1 * p1[i].z;
    const float y3 = wy0 * p0[i].w + wy1 * p1[i].w;
    float yl = __shfl_up(y3, 1, 64);   if (gg == 0)  yl = y0;   // col 4g-1 clamp
    float yr = __shfl_down(y0, 1, 64); if (gg == 31) yr = y3;   // col 4g+4 clamp
    float P[8];
    P[0] = sigAB(yl, y0); P[1] = sigBA(y0, y1);
    P[2] = sigAB(y0, y1); P[3] = sigBA(y1, y2);
    P[4] = sigAB(y1, y2); P[5] = sigBA(y2, y3);
    P[6] = sigAB(y2, y3); P[7] = sigBA(y3, yr);
    uint4 s;
    s.x = pk2(P[0], P[1]); s.y = pk2(P[2], P[3]);
    s.z = pk2(P[4], P[5]); s.w = pk2(P[6], P[7]);
    const int ks = gg >> 2, kgw = gg & 3;
    const int slot = kgw * 16 + (((n & 15) ^ ks ^ (kgw << 1)) & 15);
    *(uint4*)&Pb[(((ks * 5 + (n >> 4)) * 64) + slot) * 8] = s;
    if (reload) {
      const float* pb = pbat + (((size_t)n) << 14);
      p0[i] = *(const float4*)(pb + (nr0 << 7) + gg * 4);
      p1[i] = *(const float4*)(pb + (nr1 << 7) + gg * 4);
    }
  }
}

// Consumer: prefetch feat(row h+1) into fnxt, then 8 k-steps MFMA from fcur
// (loaded last iter) against Pb. Read slot = kg*16 + ((ch16^ks^(kg<<1))&15).
__device__ __forceinline__ void cons_row(
    const float* __restrict__ fwave, int h,
    const unsigned short* __restrict__ Pb,
    float4 (&fcur)[16], float4 (&fnxt)[16], bool prefetch,
    f32x4 (&acc)[5], int ch16, int kg) {
  if (prefetch) {
    const float* fb = fwave + (h + 1) * 256;
    #pragma unroll
    for (int ks = 0; ks < 8; ++ks) {
      const int pw = ks * 32 + kg * 8;
      fnxt[2 * ks]     = *(const float4*)(fb + pw);
      fnxt[2 * ks + 1] = *(const float4*)(fb + pw + 4);
    }
    SCHED_FENCE();
  }
  #pragma unroll
  for (int ks = 0; ks < 8; ++ks) {
    const float4 f0 = fcur[2 * ks], f1 = fcur[2 * ks + 1];
    union { uint4 u; bf16x8 v; } bu;
    bu.u.x = pk2(f0.x, f0.y); bu.u.y = pk2(f0.z, f0.w);
    bu.u.z = pk2(f1.x, f1.y); bu.u.w = pk2(f1.z, f1.w);
    const int slot = kg * 16 + ((ch16 ^ ks ^ (kg << 1)) & 15);
    #pragma unroll
    for (int m = 0; m < 5; ++m) {
      const bf16x8 af = *(const bf16x8*)&Pb[(((ks * 5 + m) * 64) + slot) * 8];
      acc[m] = __builtin_amdgcn_mfma_f32_16x16x32_bf16(af, bu.v, acc[m], 0, 0, 0);
    }
  }
}

// ---------------- Kernel 1: assemble partials ----------------
// grid = 256 blocks (1/CU), 512 threads (8 waves: 4 producer + 4 consumer).
// LDS 2x40.5 KB (odd size forces 1 block/CU). Per iter r: producers write
// P(row r+1) -> Pfrag[(r+1)&1]; consumers MFMA row r from Pfrag[r&1] with
// feat regs loaded last iter; lgkm-only barrier (no vmcnt drain, per-role
// queues ride through).
__global__ __launch_bounds__(512, 2) void k_assemble(
    const float* __restrict__ feat, const float* __restrict__ pred,
    float* __restrict__ partial) {
  __shared__ __align__(16) unsigned short Pfrag[2][20736];  // 2x40.5 KB

  const int tid = threadIdx.x;
  const int b  = blockIdx.x >> 5;
  const int rb = blockIdx.x & 31;
  const int h0 = rb * ROWS;
  const bool producer = tid < 256;
  // producer coords
  const int gg = tid & 31, nb = (tid >> 5) & 7;
  // consumer coords
  const int ctid = tid & 255;
  const int cwid = ctid >> 6, l = ctid & 63;
  const int ch16 = l & 15, kg = l >> 4, c0 = cwid << 4;

  const float* pbat  = pred + (((size_t)(b * 80)) << 14);
  const float* fwave = feat + (((size_t)(b * 64 + c0 + ch16)) << 16);

  float4 p0[10], p1[10];
  float4 fA[16], fB[16];
  f32x4 acc[5] = {};

  // ---- Prologue.
  if (producer) {
    const int j = h0 >> 1;                       // h0 even
    const int r0 = (j > 0) ? j - 1 : 0, r1 = j;
    #pragma unroll
    for (int i = 0; i < 10; ++i) {
      const float* pb = pbat + (((size_t)(nb + 8 * i)) << 14);
      p0[i] = *(const float4*)(pb + (r0 << 7) + gg * 4);
      p1[i] = *(const float4*)(pb + (r1 << 7) + gg * 4);
    }
    SCHED_FENCE();
    // process row h0 (even); reload pred rows for row h0+1 (odd): (j1, j1+1)
    const int j1 = (h0 + 1) >> 1;
    prod_row<0>(pbat, Pfrag[0], p0, p1, j1, (j1 < 127) ? j1 + 1 : 127, true, gg, nb);
  } else {
    const float* fb = fwave + h0 * 256;
    #pragma unroll
    for (int ks = 0; ks < 8; ++ks) {
      const int pw = ks * 32 + kg * 8;
      fA[2 * ks]     = *(const float4*)(fb + pw);
      fA[2 * ks + 1] = *(const float4*)(fb + pw + 4);
    }
    SCHED_FENCE();
  }
  LGKM_BARRIER();

  // ---- Main loop.
  #pragma unroll
  for (int r = 0; r < ROWS; ++r) {
    const int x = r + 1;                 // row produced this iter
    if (producer) {
      if (x < ROWS) {
        // pred rows for row x+1 (reload targets)
        const int hn = h0 + x + 1;
        const int jn = hn >> 1;
        int nr0, nr1;
        if ((hn & 1) == 0) { nr0 = (jn > 0) ? jn - 1 : 0; nr1 = jn; }
        else               { nr0 = jn; nr1 = (jn < 127) ? jn + 1 : 127; }
        const bool rld = (x + 1) < ROWS;
        if ((x & 1) == 1) prod_row<1>(pbat, Pfrag[x & 1], p0, p1, nr0, nr1, rld, gg, nb);
        else              prod_row<0>(pbat, Pfrag[x & 1], p0, p1, nr0, nr1, rld, gg, nb);
      }
    } else {
      if ((r & 1) == 0) cons_row(fwave, h0 + r, Pfrag[r & 1], fA, fB, x < ROWS, acc, ch16, kg);
      else              cons_row(fwave, h0 + r, Pfrag[r & 1], fB, fA, x < ROWS, acc, ch16, kg);
    }
    SCHED_FENCE();
    LGKM_BARRIER();
  }

  // ---- Epilogue: consumers write partial (f32).
  // D frag: col = lane&15 (channel), row = (lane>>4)*4 + q (class).
  if (!producer) {
    float* po = partial + ((size_t)(b * NPART + rb)) * (80 * 64);
    #pragma unroll
    for (int m = 0; m < 5; ++m) {
      #pragma unroll
      for (int q = 0; q < 4; ++q) {
        const int n = m * 16 + kg * 4 + q;
        po[n * 64 + c0 + ch16] = acc[m][q];
      }
    }
  }
}

// ---------------- Kernel 2: reduce + head-update chain ----------------
__device__ __forceinline__ float wred64(float v) {
  #pragma unroll
  for (int off = 32; off > 0; off >>= 1) v += __shfl_xor(v, off, 64);
  return v;
}
__device__ __forceinline__ float lnorm(float x, const float* __restrict__ g,
                                       const float* __restrict__ be, int l) {
  const float m = wred64(x) * 0.015625f;
  const float d = x - m;
  const float var = wred64(d * d) * 0.015625f;
  return d * rsqrtf(var + 1e-5f) * g[l] + be[l];
}
__device__ __forceinline__ float sigmf(float x) {
  return __builtin_amdgcn_rcpf(1.0f + __builtin_amdgcn_exp2f(-1.44269504f * x));
}

// grid = 640 blocks (one per output row), 256 threads.
__global__ __launch_bounds__(256) void k_head(
    const float* __restrict__ partial, const float* __restrict__ head,
    const float* __restrict__ Wpt, const float* __restrict__ bpt,
    const float* __restrict__ Wht, const float* __restrict__ bht,
    const float* __restrict__ Wpg, const float* __restrict__ bpg,
    const float* __restrict__ Whg, const float* __restrict__ bhg,
    const float* __restrict__ Wfc, const float* __restrict__ bfc,
    const float* __restrict__ g_pin, const float* __restrict__ be_pin,
    const float* __restrict__ g_hin, const float* __restrict__ be_hin,
    const float* __restrict__ g_pout, const float* __restrict__ be_pout,
    const float* __restrict__ g_hout, const float* __restrict__ be_hout,
    const float* __restrict__ g_fc, const float* __restrict__ be_fc,
    float* __restrict__ out, int npart) {
  __shared__ float red[4][64];
  __shared__ float buf[4][64];   // a, hd, gate, upd
  const int tid = threadIdx.x, c = tid & 63, q = tid >> 6;
  const int r = blockIdx.x;              // [0,640)
  const int b = r / 80, n = r % 80;
  const int npq = npart >> 2;

  const float* pp = partial + ((size_t)b * npart + (size_t)q * npq) * 5120 + n * 64 + c;
  float s = 0.f;
  #pragma unroll 8
  for (int jj = 0; jj < npq; ++jj) s += pp[(size_t)jj * 5120];
  red[q][c] = s;
  __syncthreads();

  if (q == 0) {
    const float a_c = red[0][c] + red[1][c] + red[2][c] + red[3][c];
    buf[0][c] = a_c;
    buf[1][c] = head[(size_t)r * 64 + c];

    float pf_in = bpt[c], pf_out = bpt[64 + c];
    float hf_in = bht[c], hf_out = bht[64 + c];
    #pragma unroll 8
    for (int k = 0; k < 64; ++k) {
      const float av = buf[0][k];
      const float hv = buf[1][k];
      pf_in  += av * Wpt[k * 128 + c];
      pf_out += av * Wpt[k * 128 + 64 + c];
      hf_in  += hv * Wht[k * 128 + c];
      hf_out += hv * Wht[k * 128 + 64 + c];
    }
    buf[2][c] = hf_in * pf_in;

    float hg = bhg[c], pg = bpg[c];
    #pragma unroll 8
    for (int k = 0; k < 64; ++k) {
      const float gv = buf[2][k];
      hg += gv * Whg[k * 64 + c];
      pg += gv * Wpg[k * 64 + c];
    }
    const float head_gate = sigmf(lnorm(hg, g_hin, be_hin, c));
    const float pred_gate = sigmf(lnorm(pg, g_pin, be_pin, c));
    const float hfo = lnorm(hf_out, g_hout, be_hout, c);
    const float pfo = lnorm(pf_out, g_pout, be_pout, c);
    buf[3][c] = pred_gate * pfo + head_gate * hfo;

    float fc = bfc[c];
    #pragma unroll 8
    for (int k = 0; k < 64; ++k)
      fc += buf[3][k] * Wfc[k * 64 + c];
    float o = lnorm(fc, g_fc, be_fc, c);
    out[(size_t)r * 64 + c] = fmaxf(o, 0.f);
  }
}

extern "C" void kernel_launch(void* const* d_in, const int* in_sizes, int n_in,
                              void* d_out, int out_size, void* d_ws, size_t ws_size,
                              hipStream_t stream) {
  const float* feat   = (const float*)d_in[0];
  const float* head   = (const float*)d_in[1];
  const float* pred   = (const float*)d_in[2];
  const float* Wpt    = (const float*)d_in[3];
  const float* bpt    = (const float*)d_in[4];
  const float* Wht    = (const float*)d_in[5];
  const float* bht    = (const float*)d_in[6];
  const float* Wpg    = (const float*)d_in[7];
  const float* bpg    = (const float*)d_in[8];
  const float* Whg    = (const float*)d_in[9];
  const float* bhg    = (const float*)d_in[10];
  const float* Wfc    = (const float*)d_in[11];
  const float* bfc    = (const float*)d_in[12];
  const float* g_pin  = (const float*)d_in[13];
  const float* be_pin = (const float*)d_in[14];
  const float* g_hin  = (const float*)d_in[15];
  const float* be_hin = (const float*)d_in[16];
  const float* g_pout = (const float*)d_in[17];
  const float* be_pout= (const float*)d_in[18];
  const float* g_hout = (const float*)d_in[19];
  const float* be_hout= (const float*)d_in[20];
  const float* g_fc   = (const float*)d_in[21];
  const float* be_fc  = (const float*)d_in[22];
  float* out = (float*)d_out;
  float* partial = (float*)d_ws;  // 8*32*5120*4 = 5.25 MB (within proven ws)

  hipLaunchKernelGGL(k_assemble, dim3(8 * NPART), dim3(512), 0, stream,
                     feat, pred, partial);
  hipLaunchKernelGGL(k_head, dim3(640), dim3(256), 0, stream,
                     partial, head, Wpt, bpt, Wht, bht, Wpg, bpg, Whg, bhg,
                     Wfc, bfc, g_pin, be_pin, g_hin, be_hin, g_pout, be_pout,
                     g_hout, be_hout, g_fc, be_fc, out, NPART);
}

// Round 13
// 60.697 us; speedup vs baseline: 5.9418x; 5.9418x over previous
//
#include <hip/hip_runtime.h>
#include <hip/hip_bf16.h>
#include <hip/hip_fp16.h>

// HeadUpdator: fused bilinear-upsample+sigmoid+einsum (MFMA) + per-row gating MLP.
// feat (8,64,256,256) f32, head (8,80,64,1) f32, pred (8,80,128,128) f32
// -> out (8,80,64,1,1) f32.
// Round-10 design (4th submit; three prior UnresponsiveContainer infra
// failures, kernel never executed): HALF-ROW high-TLP kernel. One block = one
// (row, half): Pfrag 20 KB, feat 8 regs, single barrier, ~95 VGPR ->
// ~20 waves/CU. Needs 42 MB ws (f16 partials, 512 slots/batch) -> gated on
// ws_size; fallback = proven round-8 kernel (63 us).

using bf16x8 = __attribute__((ext_vector_type(8))) short;
using f32x4  = __attribute__((ext_vector_type(4))) float;

#define SCHED_FENCE() __builtin_amdgcn_sched_barrier(0)
#define LGKM_BARRIER() do { \
  asm volatile("s_waitcnt lgkmcnt(0)" ::: "memory"); \
  __builtin_amdgcn_s_barrier(); } while (0)

__device__ __forceinline__ unsigned pk2(float lo, float hi) {
  union { __hip_bfloat162 h2; unsigned u; } cv;
  cv.h2 = __float22bfloat162_rn(make_float2(lo, hi));
  return cv.u;
}
// sigmoid(0.25a + 0.75b), -log2e folded into the lerp weights
__device__ __forceinline__ float sigAB(float a, float b) {
  return __builtin_amdgcn_rcpf(1.0f + __builtin_amdgcn_exp2f(-0.36067376f * a - 1.08202128f * b));
}
// sigmoid(0.75a + 0.25b)
__device__ __forceinline__ float sigBA(float a, float b) {
  return __builtin_amdgcn_rcpf(1.0f + __builtin_amdgcn_exp2f(-1.08202128f * a - 0.36067376f * b));
}

// ---------------- Kernel 1a: half-row assemble (big ws) ----------------
// grid = 4096 (8 b x 256 h x 2 half), 256 threads, LDS 20 KB, VGPR cap 128.
// Pred thread map: gg = tid&15 (16 px-groups of 4 cols), nbp = tid>>4;
// n = nbp + 16*i, i<5. Lane gg holds pred cols base+4gg..+3 (base = half*64,
// 16B aligned); halo: scalar col (64-half); shfl within 16-lane segments.
// Pfrag: 20 frags (ks 0..3 x m 0..4) of 1 KB; slot bijection (r8 family,
// measured 0 conflicts): write slot = kgw*16 + ((nbp^ks^(kgw<<1))&15),
// read slot = kg*16 + ((ch16^ks^(kg<<1))&15).
__global__ __launch_bounds__(256, 4) void k_assemble_half(
    const float* __restrict__ feat, const float* __restrict__ pred,
    __half* __restrict__ partial) {
  __shared__ __align__(16) unsigned short Pfrag[20 * 64 * 8];  // 20 KB

  // XCD-chunked bijective swizzle (nwg=4096): XCD x owns logical [x*512,(x+1)*512)
  // = exactly batch b=x -> pred L2 locality per XCD.
  const int bid = blockIdx.x;
  const int wg  = (bid & 7) * 512 + (bid >> 3);
  const int half = wg & 1;
  const int h    = (wg >> 1) & 255;
  const int b    = wg >> 9;

  const int tid = threadIdx.x;
  const int gg = tid & 15, nbp = tid >> 4;           // pred-phase coords
  const int wid = tid >> 6, l = tid & 63;            // mfma-phase coords
  const int ch16 = l & 15, kg = l >> 4, c0 = wid << 4;

  const int j = h >> 1;
  int r0, r1; float wy0, wy1;
  if ((h & 1) == 0) { r0 = (j > 0) ? j - 1 : 0; r1 = j; wy0 = 0.25f; wy1 = 0.75f; }
  else              { r0 = j; r1 = (j < 127) ? j + 1 : 127; wy0 = 0.75f; wy1 = 0.25f; }

  const int cbase = half << 6;          // 0 or 64 (16B aligned)
  const int csc   = 64 - half;          // halo col: 64 (half0 right) / 63 (half1 left)
  const float* pbat = pred + (((size_t)(b * 80)) << 14);

  // ---- pred float4 batch (10 loads, loop-carried -> stays in flight).
  float4 p0[5], p1[5];
  #pragma unroll
  for (int i = 0; i < 5; ++i) {
    const float* pb = pbat + (((size_t)(nbp + 16 * i)) << 14);
    p0[i] = *(const float4*)(pb + (r0 << 7) + cbase + 4 * gg);
    p1[i] = *(const float4*)(pb + (r1 << 7) + cbase + 4 * gg);
  }

  // ---- lerp + sigmoid -> Pfrag.
  #pragma unroll
  for (int i = 0; i < 5; ++i) {
    const int n = nbp + 16 * i;
    const float* pb = pbat + (((size_t)n) << 14);
    const float sc = wy0 * pb[(r0 << 7) + csc] + wy1 * pb[(r1 << 7) + csc];
    const float y0 = wy0 * p0[i].x + wy1 * p1[i].x;
    const float y1 = wy0 * p0[i].y + wy1 * p1[i].y;
    const float y2 = wy0 * p0[i].z + wy1 * p1[i].z;
    const float y3 = wy0 * p0[i].w + wy1 * p1[i].w;
    float yl = __shfl_up(y3, 1, 16);
    float yr = __shfl_down(y0, 1, 16);
    if (gg == 0)  yl = half ? sc : y0;   // left edge: scalar col 63 / clamp
    if (gg == 15) yr = half ? y3 : sc;   // right edge: clamp(col128->127) / scalar col 64
    float P[8];
    P[0] = sigAB(yl, y0); P[1] = sigBA(y0, y1);
    P[2] = sigAB(y0, y1); P[3] = sigBA(y1, y2);
    P[4] = sigAB(y1, y2); P[5] = sigBA(y2, y3);
    P[6] = sigAB(y2, y3); P[7] = sigBA(y3, yr);
    uint4 s;
    s.x = pk2(P[0], P[1]); s.y = pk2(P[2], P[3]);
    s.z = pk2(P[4], P[5]); s.w = pk2(P[6], P[7]);
    const int ks = gg >> 2, kgw = gg & 3;
    const int slot = kgw * 16 + ((nbp ^ ks ^ (kgw << 1)) & 15);
    *(uint4*)&Pfrag[(((ks * 5 + i) * 64) + slot) * 8] = s;
  }
  __syncthreads();   // nothing else outstanding; plain barrier is fine

  // ---- feat loads + 20 MFMA (4 ks x 5 m). Single pass, no second barrier.
  const float* fb = feat + (((size_t)(b * 64 + c0 + ch16)) << 16) + h * 256 + (half << 7);
  f32x4 acc[5] = {};
  #pragma unroll
  for (int ks = 0; ks < 4; ++ks) {
    const int pw = ks * 32 + kg * 8;
    const float4 f0 = *(const float4*)(fb + pw);
    const float4 f1 = *(const float4*)(fb + pw + 4);
    union { uint4 u; bf16x8 v; } bu;
    bu.u.x = pk2(f0.x, f0.y); bu.u.y = pk2(f0.z, f0.w);
    bu.u.z = pk2(f1.x, f1.y); bu.u.w = pk2(f1.z, f1.w);
    const int slot = kg * 16 + ((ch16 ^ ks ^ (kg << 1)) & 15);
    #pragma unroll
    for (int m = 0; m < 5; ++m) {
      const bf16x8 af = *(const bf16x8*)&Pfrag[(((ks * 5 + m) * 64) + slot) * 8];
      acc[m] = __builtin_amdgcn_mfma_f32_16x16x32_bf16(af, bu.v, acc[m], 0, 0, 0);
    }
  }

  // D frag: col = lane&15 (channel), row = (lane>>4)*4 + q (class).
  __half* po = partial + ((size_t)(b * 512 + h * 2 + half)) * (80 * 64);
  #pragma unroll
  for (int m = 0; m < 5; ++m) {
    #pragma unroll
    for (int q = 0; q < 4; ++q) {
      const int n = m * 16 + kg * 4 + q;
      po[n * 64 + c0 + ch16] = __float2half(acc[m][q]);
    }
  }
}

// ---------------- Kernel 1b: round-8 fallback (ws < 42 MB) ----------------
__global__ __launch_bounds__(256) void k_assemble_full(
    const float* __restrict__ feat, const float* __restrict__ pred,
    __half* __restrict__ partial) {
  __shared__ __align__(16) unsigned short Pfrag[40 * 64 * 8];  // 40 KB

  const int tid = threadIdx.x;
  const int b  = blockIdx.x >> 7;
  const int rb = blockIdx.x & 127;
  const int wid = tid >> 6, l = tid & 63;
  const int ch16 = l & 15, kg = l >> 4;
  const int c0 = wid << 4;
  const int h0 = rb * 2;
  const int gg = tid & 31, nb = tid >> 5;

  f32x4 acc[5] = {};
  const float* fwave = feat + (((size_t)(b * 64 + c0 + ch16)) << 16);
  const float* pbat  = pred + (((size_t)(b * 80)) << 14);

  #pragma unroll
  for (int r = 0; r < 2; ++r) {
    const int h = h0 + r;
    const int j = h >> 1;
    int r0, r1; float wy0, wy1;
    if ((h & 1) == 0) { r0 = (j > 0) ? j - 1 : 0; r1 = j; wy0 = 0.25f; wy1 = 0.75f; }
    else              { r0 = j; r1 = (j < 127) ? j + 1 : 127; wy0 = 0.75f; wy1 = 0.25f; }

    float4 p0[10], p1[10];
    #pragma unroll
    for (int i = 0; i < 10; ++i) {
      const float* pb = pbat + (((size_t)(nb + 8 * i)) << 14);
      p0[i] = *(const float4*)(pb + (r0 << 7) + gg * 4);
      p1[i] = *(const float4*)(pb + (r1 << 7) + gg * 4);
    }
    SCHED_FENCE();

    const float* fb = fwave + h * 256;
    float4 f[16];
    #pragma unroll
    for (int ks = 0; ks < 8; ++ks) {
      const int pw = ks * 32 + kg * 8;
      f[2 * ks]     = *(const float4*)(fb + pw);
      f[2 * ks + 1] = *(const float4*)(fb + pw + 4);
    }
    SCHED_FENCE();

    #pragma unroll
    for (int i = 0; i < 10; ++i) {
      const int n = nb + 8 * i;
      const float y0 = wy0 * p0[i].x + wy1 * p1[i].x;
      const float y1 = wy0 * p0[i].y + wy1 * p1[i].y;
      const float y2 = wy0 * p0[i].z + wy1 * p1[i].z;
      const float y3 = wy0 * p0[i].w + wy1 * p1[i].w;
      float yl = __shfl_up(y3, 1, 64);   if (gg == 0)  yl = y0;
      float yr = __shfl_down(y0, 1, 64); if (gg == 31) yr = y3;
      float P[8];
      P[0] = sigAB(yl, y0); P[1] = sigBA(y0, y1);
      P[2] = sigAB(y0, y1); P[3] = sigBA(y1, y2);
      P[4] = sigAB(y1, y2); P[5] = sigBA(y2, y3);
      P[6] = sigAB(y2, y3); P[7] = sigBA(y3, yr);
      uint4 s;
      s.x = pk2(P[0], P[1]); s.y = pk2(P[2], P[3]);
      s.z = pk2(P[4], P[5]); s.w = pk2(P[6], P[7]);
      const int ks = gg >> 2, kgw = gg & 3;
      const int slot = kgw * 16 + (((n & 15) ^ ks ^ (kgw << 1)) & 15);
      *(uint4*)&Pfrag[(((ks * 5 + (n >> 4)) * 64) + slot) * 8] = s;
    }
    LGKM_BARRIER();

    #pragma unroll
    for (int ks = 0; ks < 8; ++ks) {
      const float4 f0 = f[2 * ks], f1 = f[2 * ks + 1];
      union { uint4 u; bf16x8 v; } bu;
      bu.u.x = pk2(f0.x, f0.y); bu.u.y = pk2(f0.z, f0.w);
      bu.u.z = pk2(f1.x, f1.y); bu.u.w = pk2(f1.z, f1.w);
      const int slot = kg * 16 + ((ch16 ^ ks ^ (kg << 1)) & 15);
      #pragma unroll
      for (int m = 0; m < 5; ++m) {
        const bf16x8 af = *(const bf16x8*)&Pfrag[(((ks * 5 + m) * 64) + slot) * 8];
        acc[m] = __builtin_amdgcn_mfma_f32_16x16x32_bf16(af, bu.v, acc[m], 0, 0, 0);
      }
    }
    LGKM_BARRIER();
  }

  __half* po = partial + ((size_t)(b * 128 + rb)) * (80 * 64);
  #pragma unroll
  for (int m = 0; m < 5; ++m) {
    #pragma unroll
    for (int q = 0; q < 4; ++q) {
      const int n = m * 16 + kg * 4 + q;
      po[n * 64 + c0 + ch16] = __float2half(acc[m][q]);
    }
  }
}

// ---------------- Kernel 2: reduce + head-update chain ----------------
__device__ __forceinline__ float wred64(float v) {
  #pragma unroll
  for (int off = 32; off > 0; off >>= 1) v += __shfl_xor(v, off, 64);
  return v;
}
__device__ __forceinline__ float lnorm(float x, const float* __restrict__ g,
                                       const float* __restrict__ be, int l) {
  const float m = wred64(x) * 0.015625f;
  const float d = x - m;
  const float var = wred64(d * d) * 0.015625f;
  return d * rsqrtf(var + 1e-5f) * g[l] + be[l];
}
__device__ __forceinline__ float sigmf(float x) {
  return __builtin_amdgcn_rcpf(1.0f + __builtin_amdgcn_exp2f(-1.44269504f * x));
}

// grid = 640 blocks (one per output row), 256 threads.
__global__ __launch_bounds__(256) void k_head(
    const __half* __restrict__ partial, const float* __restrict__ head,
    const float* __restrict__ Wpt, const float* __restrict__ bpt,
    const float* __restrict__ Wht, const float* __restrict__ bht,
    const float* __restrict__ Wpg, const float* __restrict__ bpg,
    const float* __restrict__ Whg, const float* __restrict__ bhg,
    const float* __restrict__ Wfc, const float* __restrict__ bfc,
    const float* __restrict__ g_pin, const float* __restrict__ be_pin,
    const float* __restrict__ g_hin, const float* __restrict__ be_hin,
    const float* __restrict__ g_pout, const float* __restrict__ be_pout,
    const float* __restrict__ g_hout, const float* __restrict__ be_hout,
    const float* __restrict__ g_fc, const float* __restrict__ be_fc,
    float* __restrict__ out, int npart) {
  __shared__ float red[4][64];
  __shared__ float buf[4][64];   // a, hd, gate, upd
  const int tid = threadIdx.x, c = tid & 63, q = tid >> 6;
  const int r = blockIdx.x;              // [0,640)
  const int b = r / 80, n = r % 80;
  const int npq = npart >> 2;

  const __half* pp = partial + ((size_t)b * npart + (size_t)q * npq) * 5120 + n * 64 + c;
  float s = 0.f;
  #pragma unroll 8
  for (int jj = 0; jj < npq; ++jj) s += __half2float(pp[(size_t)jj * 5120]);
  red[q][c] = s;
  __syncthreads();

  if (q == 0) {
    const float a_c = red[0][c] + red[1][c] + red[2][c] + red[3][c];
    buf[0][c] = a_c;
    buf[1][c] = head[(size_t)r * 64 + c];

    float pf_in = bpt[c], pf_out = bpt[64 + c];
    float hf_in = bht[c], hf_out = bht[64 + c];
    #pragma unroll 8
    for (int k = 0; k < 64; ++k) {
      const float av = buf[0][k];
      const float hv = buf[1][k];
      pf_in  += av * Wpt[k * 128 + c];
      pf_out += av * Wpt[k * 128 + 64 + c];
      hf_in  += hv * Wht[k * 128 + c];
      hf_out += hv * Wht[k * 128 + 64 + c];
    }
    buf[2][c] = hf_in * pf_in;

    float hg = bhg[c], pg = bpg[c];
    #pragma unroll 8
    for (int k = 0; k < 64; ++k) {
      const float gv = buf[2][k];
      hg += gv * Whg[k * 64 + c];
      pg += gv * Wpg[k * 64 + c];
    }
    const float head_gate = sigmf(lnorm(hg, g_hin, be_hin, c));
    const float pred_gate = sigmf(lnorm(pg, g_pin, be_pin, c));
    const float hfo = lnorm(hf_out, g_hout, be_hout, c);
    const float pfo = lnorm(pf_out, g_pout, be_pout, c);
    buf[3][c] = pred_gate * pfo + head_gate * hfo;

    float fc = bfc[c];
    #pragma unroll 8
    for (int k = 0; k < 64; ++k)
      fc += buf[3][k] * Wfc[k * 64 + c];
    float o = lnorm(fc, g_fc, be_fc, c);
    out[(size_t)r * 64 + c] = fmaxf(o, 0.f);
  }
}

extern "C" void kernel_launch(void* const* d_in, const int* in_sizes, int n_in,
                              void* d_out, int out_size, void* d_ws, size_t ws_size,
                              hipStream_t stream) {
  const float* feat   = (const float*)d_in[0];
  const float* head   = (const float*)d_in[1];
  const float* pred   = (const float*)d_in[2];
  const float* Wpt    = (const float*)d_in[3];
  const float* bpt    = (const float*)d_in[4];
  const float* Wht    = (const float*)d_in[5];
  const float* bht    = (const float*)d_in[6];
  const float* Wpg    = (const float*)d_in[7];
  const float* bpg    = (const float*)d_in[8];
  const float* Whg    = (const float*)d_in[9];
  const float* bhg    = (const float*)d_in[10];
  const float* Wfc    = (const float*)d_in[11];
  const float* bfc    = (const float*)d_in[12];
  const float* g_pin  = (const float*)d_in[13];
  const float* be_pin = (const float*)d_in[14];
  const float* g_hin  = (const float*)d_in[15];
  const float* be_hin = (const float*)d_in[16];
  const float* g_pout = (const float*)d_in[17];
  const float* be_pout= (const float*)d_in[18];
  const float* g_hout = (const float*)d_in[19];
  const float* be_hout= (const float*)d_in[20];
  const float* g_fc   = (const float*)d_in[21];
  const float* be_fc  = (const float*)d_in[22];
  float* out = (float*)d_out;
  __half* partial = (__half*)d_ws;

  const bool big = ws_size >= (size_t)8 * 512 * 5120 * 2;  // 41.94 MB
  const int npart = big ? 512 : 128;

  if (big)
    hipLaunchKernelGGL(k_assemble_half, dim3(4096), dim3(256), 0, stream,
                       feat, pred, partial);
  else
    hipLaunchKernelGGL(k_assemble_full, dim3(1024), dim3(256), 0, stream,
                       feat, pred, partial);

  hipLaunchKernelGGL(k_head, dim3(640), dim3(256), 0, stream,
                     partial, head, Wpt, bpt, Wht, bht, Wpg, bpg, Whg, bhg,
                     Wfc, bfc, g_pin, be_pin, g_hin, be_hin, g_pout, be_pout,
                     g_hout, be_hout, g_fc, be_fc, out, npart);
}